// Round 1
// baseline (983.174 us; speedup 1.0000x reference)
//
#include <hip/hip_runtime.h>
#include <math.h>

#define N_NODES 100000
#define N_EDGES 1600000
#define D 64
#define DOUT 10
#define CAP 64

// ---------------- CSR-ish bucket build ----------------
__global__ void fill_kernel(const int* __restrict__ src, const int* __restrict__ dst,
                            int* __restrict__ cnt, int* __restrict__ bucket) {
    int e = blockIdx.x * blockDim.x + threadIdx.x;
    if (e >= N_EDGES) return;
    int d = dst[e];
    int p = atomicAdd(&cnt[d], 1);
    if (p < CAP) bucket[d * CAP + p] = src[e];
}

__device__ __forceinline__ float readlane_f(float v, int l) {
    return __int_as_float(__builtin_amdgcn_readlane(__float_as_int(v), l));
}

// ---------------- Hidden layers: gather + dual GEMM(64x64) + bias + relu ----------------
// One wave per node (grid-stride). lane = feature index for gather, = output col for GEMM.
// W_out / W_root columns live in 128 VGPRs per lane, loaded once per wave.
__global__ __launch_bounds__(256) void layer64_kernel(
    const float* __restrict__ in, float* __restrict__ out,
    const int* __restrict__ cnt, const int* __restrict__ bucket,
    const float* __restrict__ W_out, const float* __restrict__ bias_v,
    const float* __restrict__ W_root) {
    int lane = threadIdx.x & 63;
    int wid = (blockIdx.x * blockDim.x + threadIdx.x) >> 6;
    int nwaves = (gridDim.x * blockDim.x) >> 6;

    float wOut[D], wRoot[D];
#pragma unroll
    for (int k = 0; k < D; ++k) wOut[k] = W_out[k * D + lane];
#pragma unroll
    for (int k = 0; k < D; ++k) wRoot[k] = W_root[k * D + lane];
    float bias = bias_v[lane];

    for (int node = wid; node < N_NODES; node += nwaves) {
        int c = cnt[node];
        int cc = c < CAP ? c : CAP;
        int bl = bucket[node * CAP + lane];   // whole index list in one coalesced load
        float agg = 0.f;
        for (int k = 0; k < cc; ++k) {
            int s = __builtin_amdgcn_readlane(bl, k);
            agg += in[s * D + lane];
        }
        float dinv = 1.0f / (float)(c > 0 ? c : 1);
        agg *= dinv;
        float xv = in[node * D + lane];

        float acc0 = bias, acc1 = 0.f;
#pragma unroll
        for (int k = 0; k < D; k += 2) {
            acc0 += readlane_f(agg, k)     * wOut[k]     + readlane_f(xv, k)     * wRoot[k];
            acc1 += readlane_f(agg, k + 1) * wOut[k + 1] + readlane_f(xv, k + 1) * wRoot[k + 1];
        }
        float r = acc0 + acc1;
        r = fmaxf(r, 0.f);
        out[node * D + lane] = r;
    }
}

// ---------------- Output layer: gather + dual GEMM(64x10) + log_softmax ----------------
__global__ __launch_bounds__(256) void layer_out_kernel(
    const float* __restrict__ in, float* __restrict__ out,
    const int* __restrict__ cnt, const int* __restrict__ bucket,
    const float* __restrict__ W_out, const float* __restrict__ bias_v,
    const float* __restrict__ W_root) {
    int lane = threadIdx.x & 63;
    int wid = (blockIdx.x * blockDim.x + threadIdx.x) >> 6;
    int nwaves = (gridDim.x * blockDim.x) >> 6;
    int jj = lane < DOUT ? lane : DOUT - 1;   // lanes >=10 duplicate col 9 (discarded)

    float wOut[D], wRoot[D];
#pragma unroll
    for (int k = 0; k < D; ++k) wOut[k] = W_out[k * DOUT + jj];
#pragma unroll
    for (int k = 0; k < D; ++k) wRoot[k] = W_root[k * DOUT + jj];
    float bias = bias_v[jj];

    for (int node = wid; node < N_NODES; node += nwaves) {
        int c = cnt[node];
        int cc = c < CAP ? c : CAP;
        int bl = bucket[node * CAP + lane];
        float agg = 0.f;
        for (int k = 0; k < cc; ++k) {
            int s = __builtin_amdgcn_readlane(bl, k);
            agg += in[s * D + lane];
        }
        float dinv = 1.0f / (float)(c > 0 ? c : 1);
        agg *= dinv;
        float xv = in[node * D + lane];

        float acc0 = bias, acc1 = 0.f;
#pragma unroll
        for (int k = 0; k < D; k += 2) {
            acc0 += readlane_f(agg, k)     * wOut[k]     + readlane_f(xv, k)     * wRoot[k];
            acc1 += readlane_f(agg, k + 1) * wOut[k + 1] + readlane_f(xv, k + 1) * wRoot[k + 1];
        }
        float v = acc0 + acc1;

        // log_softmax over the 10 outputs, held in lanes 0..9; reduce within 16-lane group
        float m = (lane < DOUT) ? v : -INFINITY;
        m = fmaxf(m, __shfl_xor(m, 1, 16));
        m = fmaxf(m, __shfl_xor(m, 2, 16));
        m = fmaxf(m, __shfl_xor(m, 4, 16));
        m = fmaxf(m, __shfl_xor(m, 8, 16));
        float e = (lane < DOUT) ? expf(v - m) : 0.f;
        float s = e;
        s += __shfl_xor(s, 1, 16);
        s += __shfl_xor(s, 2, 16);
        s += __shfl_xor(s, 4, 16);
        s += __shfl_xor(s, 8, 16);
        if (lane < DOUT) out[node * DOUT + lane] = v - m - logf(s);
    }
}

extern "C" void kernel_launch(void* const* d_in, const int* in_sizes, int n_in,
                              void* d_out, int out_size, void* d_ws, size_t ws_size,
                              hipStream_t stream) {
    const float* x       = (const float*)d_in[0];
    const int*   ei      = (const int*)d_in[1];
    const int*   src     = ei;            // edge_index[0]
    const int*   dst     = ei + N_EDGES;  // edge_index[1]
    const float* W_out0  = (const float*)d_in[2];
    const float* b0      = (const float*)d_in[3];
    const float* W_root0 = (const float*)d_in[4];
    const float* W_out1  = (const float*)d_in[5];
    const float* b1      = (const float*)d_in[6];
    const float* W_root1 = (const float*)d_in[7];
    const float* W_out2  = (const float*)d_in[8];
    const float* b2      = (const float*)d_in[9];
    const float* W_root2 = (const float*)d_in[10];
    float* outp = (float*)d_out;

    // workspace layout: h0[N*64] f32 | h1[N*64] f32 | cnt[N] i32 | bucket[N*64] i32  (~77 MB)
    float* h0     = (float*)d_ws;
    float* h1     = h0 + (size_t)N_NODES * D;
    int*   cnt    = (int*)(h1 + (size_t)N_NODES * D);
    int*   bucket = cnt + N_NODES;

    hipMemsetAsync(cnt, 0, N_NODES * sizeof(int), stream);
    fill_kernel<<<(N_EDGES + 255) / 256, 256, 0, stream>>>(src, dst, cnt, bucket);

    const int blocks = 2048;
    layer64_kernel<<<blocks, 256, 0, stream>>>(x,  h0, cnt, bucket, W_out0, b0, W_root0);
    layer64_kernel<<<blocks, 256, 0, stream>>>(h0, h1, cnt, bucket, W_out1, b1, W_root1);
    layer_out_kernel<<<blocks, 256, 0, stream>>>(h1, outp, cnt, bucket, W_out2, b2, W_root2);
}

// Round 2
// 658.212 us; speedup vs baseline: 1.4937x; 1.4937x over previous
//
#include <hip/hip_runtime.h>
#include <math.h>

#define N_NODES 100000
#define N_EDGES 1600000
#define D 64
#define DOUT 10
#define CAP 64

// ---------------- bucket build: one int atomic per edge ----------------
__global__ void fill_kernel(const int* __restrict__ src, const int* __restrict__ dst,
                            int* __restrict__ cnt, int* __restrict__ bucket) {
    int e = blockIdx.x * blockDim.x + threadIdx.x;
    if (e >= N_EDGES) return;
    int d = dst[e];
    int p = atomicAdd(&cnt[d], 1);
    if (p < CAP) bucket[d * CAP + p] = src[e];
}

__device__ __forceinline__ float readlane_f(float v, int l) {
    return __int_as_float(__builtin_amdgcn_readlane(__float_as_int(v), l));
}

// ---------------- hidden layer: gather(+mean) + dual GEMM(64x64) + bias + relu --------
// One wave per node (grid-stride). lane = feature for gather, = output col for GEMM.
// Weights live in LDS (loaded once per block); gather unrolled x8 for MLP.
__global__ __launch_bounds__(256) void layer64_kernel(
    const float* __restrict__ in, float* __restrict__ out,
    const int* __restrict__ cnt, const int* __restrict__ bucket,
    const float* __restrict__ W_out, const float* __restrict__ bias_v,
    const float* __restrict__ W_root) {
    __shared__ float lw_out[D * D];
    __shared__ float lw_root[D * D];
    int tid = threadIdx.x;
    for (int i = tid * 4; i < D * D; i += 256 * 4) {
        *(float4*)&lw_out[i]  = *(const float4*)&W_out[i];
        *(float4*)&lw_root[i] = *(const float4*)&W_root[i];
    }
    __syncthreads();

    int lane = tid & 63;
    int wid = (blockIdx.x * blockDim.x + tid) >> 6;
    int nwaves = (gridDim.x * blockDim.x) >> 6;
    float bias = bias_v[lane];

    for (int node = wid; node < N_NODES; node += nwaves) {
        int c = cnt[node];
        int cc = c < CAP ? c : CAP;
        int bl = bucket[node * CAP + lane];      // whole index list, one coalesced 256B read
        float xv = in[(size_t)node * D + lane];  // issue early

        float a0 = 0.f, a1 = 0.f, a2 = 0.f, a3 = 0.f,
              a4 = 0.f, a5 = 0.f, a6 = 0.f, a7 = 0.f;
        int k = 0;
        for (; k + 8 <= cc; k += 8) {
            int s0 = __builtin_amdgcn_readlane(bl, k);
            int s1 = __builtin_amdgcn_readlane(bl, k + 1);
            int s2 = __builtin_amdgcn_readlane(bl, k + 2);
            int s3 = __builtin_amdgcn_readlane(bl, k + 3);
            int s4 = __builtin_amdgcn_readlane(bl, k + 4);
            int s5 = __builtin_amdgcn_readlane(bl, k + 5);
            int s6 = __builtin_amdgcn_readlane(bl, k + 6);
            int s7 = __builtin_amdgcn_readlane(bl, k + 7);
            a0 += in[(size_t)s0 * D + lane];
            a1 += in[(size_t)s1 * D + lane];
            a2 += in[(size_t)s2 * D + lane];
            a3 += in[(size_t)s3 * D + lane];
            a4 += in[(size_t)s4 * D + lane];
            a5 += in[(size_t)s5 * D + lane];
            a6 += in[(size_t)s6 * D + lane];
            a7 += in[(size_t)s7 * D + lane];
        }
        for (; k < cc; ++k) {
            int s = __builtin_amdgcn_readlane(bl, k);
            a0 += in[(size_t)s * D + lane];
        }
        float agg = ((a0 + a1) + (a2 + a3)) + ((a4 + a5) + (a6 + a7));
        agg *= 1.0f / (float)(c > 0 ? c : 1);

        float acc0 = bias, acc1 = 0.f;
#pragma unroll
        for (int k2 = 0; k2 < D; k2 += 2) {
            float ak0 = readlane_f(agg, k2),     xk0 = readlane_f(xv, k2);
            float ak1 = readlane_f(agg, k2 + 1), xk1 = readlane_f(xv, k2 + 1);
            acc0 += ak0 * lw_out[k2 * D + lane]       + xk0 * lw_root[k2 * D + lane];
            acc1 += ak1 * lw_out[(k2 + 1) * D + lane] + xk1 * lw_root[(k2 + 1) * D + lane];
        }
        float r = acc0 + acc1;
        out[(size_t)node * D + lane] = fmaxf(r, 0.f);
    }
}

// ---------------- output layer: gather + dual GEMM(64x10) + log_softmax ----------------
__global__ __launch_bounds__(256) void layer_out_kernel(
    const float* __restrict__ in, float* __restrict__ out,
    const int* __restrict__ cnt, const int* __restrict__ bucket,
    const float* __restrict__ W_out, const float* __restrict__ bias_v,
    const float* __restrict__ W_root) {
    __shared__ float lw_out[D * DOUT];
    __shared__ float lw_root[D * DOUT];
    int tid = threadIdx.x;
    for (int i = tid; i < D * DOUT; i += 256) {
        lw_out[i]  = W_out[i];
        lw_root[i] = W_root[i];
    }
    __syncthreads();

    int lane = tid & 63;
    int wid = (blockIdx.x * blockDim.x + tid) >> 6;
    int nwaves = (gridDim.x * blockDim.x) >> 6;
    int jj = lane < DOUT ? lane : DOUT - 1;  // lanes >=10 duplicate col 9 (discarded)
    float bias = bias_v[jj];

    for (int node = wid; node < N_NODES; node += nwaves) {
        int c = cnt[node];
        int cc = c < CAP ? c : CAP;
        int bl = bucket[node * CAP + lane];
        float xv = in[(size_t)node * D + lane];

        float a0 = 0.f, a1 = 0.f, a2 = 0.f, a3 = 0.f,
              a4 = 0.f, a5 = 0.f, a6 = 0.f, a7 = 0.f;
        int k = 0;
        for (; k + 8 <= cc; k += 8) {
            int s0 = __builtin_amdgcn_readlane(bl, k);
            int s1 = __builtin_amdgcn_readlane(bl, k + 1);
            int s2 = __builtin_amdgcn_readlane(bl, k + 2);
            int s3 = __builtin_amdgcn_readlane(bl, k + 3);
            int s4 = __builtin_amdgcn_readlane(bl, k + 4);
            int s5 = __builtin_amdgcn_readlane(bl, k + 5);
            int s6 = __builtin_amdgcn_readlane(bl, k + 6);
            int s7 = __builtin_amdgcn_readlane(bl, k + 7);
            a0 += in[(size_t)s0 * D + lane];
            a1 += in[(size_t)s1 * D + lane];
            a2 += in[(size_t)s2 * D + lane];
            a3 += in[(size_t)s3 * D + lane];
            a4 += in[(size_t)s4 * D + lane];
            a5 += in[(size_t)s5 * D + lane];
            a6 += in[(size_t)s6 * D + lane];
            a7 += in[(size_t)s7 * D + lane];
        }
        for (; k < cc; ++k) {
            int s = __builtin_amdgcn_readlane(bl, k);
            a0 += in[(size_t)s * D + lane];
        }
        float agg = ((a0 + a1) + (a2 + a3)) + ((a4 + a5) + (a6 + a7));
        agg *= 1.0f / (float)(c > 0 ? c : 1);

        float acc0 = bias, acc1 = 0.f;
#pragma unroll
        for (int k2 = 0; k2 < D; k2 += 2) {
            float ak0 = readlane_f(agg, k2),     xk0 = readlane_f(xv, k2);
            float ak1 = readlane_f(agg, k2 + 1), xk1 = readlane_f(xv, k2 + 1);
            acc0 += ak0 * lw_out[k2 * DOUT + jj]       + xk0 * lw_root[k2 * DOUT + jj];
            acc1 += ak1 * lw_out[(k2 + 1) * DOUT + jj] + xk1 * lw_root[(k2 + 1) * DOUT + jj];
        }
        float v = acc0 + acc1;

        // log_softmax over 10 cols held in lanes 0..9; reduce within 16-lane group
        float m = (lane < DOUT) ? v : -INFINITY;
        m = fmaxf(m, __shfl_xor(m, 1, 16));
        m = fmaxf(m, __shfl_xor(m, 2, 16));
        m = fmaxf(m, __shfl_xor(m, 4, 16));
        m = fmaxf(m, __shfl_xor(m, 8, 16));
        float e = (lane < DOUT) ? expf(v - m) : 0.f;
        float s = e;
        s += __shfl_xor(s, 1, 16);
        s += __shfl_xor(s, 2, 16);
        s += __shfl_xor(s, 4, 16);
        s += __shfl_xor(s, 8, 16);
        if (lane < DOUT) out[(size_t)node * DOUT + lane] = v - m - logf(s);
    }
}

extern "C" void kernel_launch(void* const* d_in, const int* in_sizes, int n_in,
                              void* d_out, int out_size, void* d_ws, size_t ws_size,
                              hipStream_t stream) {
    const float* x       = (const float*)d_in[0];
    const int*   ei      = (const int*)d_in[1];
    const int*   src     = ei;            // edge_index[0]
    const int*   dst     = ei + N_EDGES;  // edge_index[1]
    const float* W_out0  = (const float*)d_in[2];
    const float* b0      = (const float*)d_in[3];
    const float* W_root0 = (const float*)d_in[4];
    const float* W_out1  = (const float*)d_in[5];
    const float* b1      = (const float*)d_in[6];
    const float* W_root1 = (const float*)d_in[7];
    const float* W_out2  = (const float*)d_in[8];
    const float* b2      = (const float*)d_in[9];
    const float* W_root2 = (const float*)d_in[10];
    float* outp = (float*)d_out;

    // workspace: h0[N*64] f32 | h1[N*64] f32 | cnt[N] i32 | bucket[N*64] i32
    float* h0     = (float*)d_ws;
    float* h1     = h0 + (size_t)N_NODES * D;
    int*   cnt    = (int*)(h1 + (size_t)N_NODES * D);
    int*   bucket = cnt + N_NODES;

    hipMemsetAsync(cnt, 0, N_NODES * sizeof(int), stream);
    fill_kernel<<<(N_EDGES + 255) / 256, 256, 0, stream>>>(src, dst, cnt, bucket);

    // 32KB LDS/block -> 5 blocks/CU; 1280 blocks = fully resident persistent grid
    const int blocks64 = 1280;
    layer64_kernel<<<blocks64, 256, 0, stream>>>(x,  h0, cnt, bucket, W_out0, b0, W_root0);
    layer64_kernel<<<blocks64, 256, 0, stream>>>(h0, h1, cnt, bucket, W_out1, b1, W_root1);
    layer_out_kernel<<<2048, 256, 0, stream>>>(h1, outp, cnt, bucket, W_out2, b2, W_root2);
}

// Round 3
// 588.060 us; speedup vs baseline: 1.6719x; 1.1193x over previous
//
#include <hip/hip_runtime.h>
#include <math.h>

#define N_NODES 100000
#define N_EDGES 1600000
#define D 64
#define DOUT 10
#define CAP 64

// ---------------- bucket build: one int atomic per edge ----------------
__global__ void fill_kernel(const int* __restrict__ src, const int* __restrict__ dst,
                            int* __restrict__ cnt, int* __restrict__ bucket) {
    int e = blockIdx.x * blockDim.x + threadIdx.x;
    if (e >= N_EDGES) return;
    int d = dst[e];
    int p = atomicAdd(&cnt[d], 1);
    if (p < CAP) bucket[d * CAP + p] = src[e];
}

__device__ __forceinline__ float readlane_f(float v, int l) {
    return __int_as_float(__builtin_amdgcn_readlane(__float_as_int(v), l));
}

// gather + mean for one node; lane = feature. bl = this lane's bucket entry.
// 8 independent chains -> 8 loads in flight.
__device__ __forceinline__ float gather_mean(const float* __restrict__ in, int lane,
                                             int c, int bl) {
    int cc = c < CAP ? c : CAP;
    float a0 = 0.f, a1 = 0.f, a2 = 0.f, a3 = 0.f,
          a4 = 0.f, a5 = 0.f, a6 = 0.f, a7 = 0.f;
    int k = 0;
    for (; k + 8 <= cc; k += 8) {
        int s0 = __builtin_amdgcn_readlane(bl, k);
        int s1 = __builtin_amdgcn_readlane(bl, k + 1);
        int s2 = __builtin_amdgcn_readlane(bl, k + 2);
        int s3 = __builtin_amdgcn_readlane(bl, k + 3);
        int s4 = __builtin_amdgcn_readlane(bl, k + 4);
        int s5 = __builtin_amdgcn_readlane(bl, k + 5);
        int s6 = __builtin_amdgcn_readlane(bl, k + 6);
        int s7 = __builtin_amdgcn_readlane(bl, k + 7);
        a0 += in[(size_t)s0 * D + lane];
        a1 += in[(size_t)s1 * D + lane];
        a2 += in[(size_t)s2 * D + lane];
        a3 += in[(size_t)s3 * D + lane];
        a4 += in[(size_t)s4 * D + lane];
        a5 += in[(size_t)s5 * D + lane];
        a6 += in[(size_t)s6 * D + lane];
        a7 += in[(size_t)s7 * D + lane];
    }
    for (; k < cc; ++k) {
        int s = __builtin_amdgcn_readlane(bl, k);
        a0 += in[(size_t)s * D + lane];
    }
    float agg = ((a0 + a1) + (a2 + a3)) + ((a4 + a5) + (a6 + a7));
    return agg / (float)(c > 0 ? c : 1);
}

// ---------------- hidden layer: gather + dual GEMM(64x64) + bias + relu ----------------
// One wave per node. lane = feature for gather, = output col for GEMM.
// Weight columns live in VGPRs (128 floats/lane); broadcast via v_readlane -> SGPR.
// __launch_bounds__(256,2): allow up to 256 VGPR so the weight arrays stay registered.
__global__ __launch_bounds__(256, 2) void layer64_kernel(
    const float* __restrict__ in, float* __restrict__ out,
    const int* __restrict__ cnt, const int* __restrict__ bucket,
    const float* __restrict__ W_out, const float* __restrict__ bias_v,
    const float* __restrict__ W_root) {
    int tid = threadIdx.x;
    int lane = tid & 63;
    int wid = (blockIdx.x * blockDim.x + tid) >> 6;
    int nwaves = (gridDim.x * blockDim.x) >> 6;

    float wOut[D], wRoot[D];
#pragma unroll
    for (int k = 0; k < D; ++k) wOut[k] = W_out[k * D + lane];
#pragma unroll
    for (int k = 0; k < D; ++k) wRoot[k] = W_root[k * D + lane];
    float bias = bias_v[lane];

    for (int node = wid; node < N_NODES; node += nwaves) {
        int c = cnt[node];
        int bl = bucket[(size_t)node * CAP + lane];  // index list, one coalesced 256B read
        float xv = in[(size_t)node * D + lane];
        float agg = gather_mean(in, lane, c, bl);

        float acc0 = bias, acc1 = 0.f;
#pragma unroll
        for (int k = 0; k < D; ++k) {
            float ak = readlane_f(agg, k);  // SGPR broadcast
            float xk = readlane_f(xv, k);
            acc0 += ak * wOut[k];
            acc1 += xk * wRoot[k];
        }
        out[(size_t)node * D + lane] = fmaxf(acc0 + acc1, 0.f);
    }
}

// ---------------- output layer: gather + dual GEMM(64x10) + log_softmax --------------
// lane = feature. Each lane holds W rows (10+10 floats); 10 butterfly reductions.
__global__ __launch_bounds__(256) void layer_out_kernel(
    const float* __restrict__ in, float* __restrict__ out,
    const int* __restrict__ cnt, const int* __restrict__ bucket,
    const float* __restrict__ W_out, const float* __restrict__ bias_v,
    const float* __restrict__ W_root) {
    int tid = threadIdx.x;
    int lane = tid & 63;
    int wid = (blockIdx.x * blockDim.x + tid) >> 6;
    int nwaves = (gridDim.x * blockDim.x) >> 6;

    float wO[DOUT], wR[DOUT], bj[DOUT];
#pragma unroll
    for (int j = 0; j < DOUT; ++j) wO[j] = W_out[lane * DOUT + j];   // W[k=lane][j]
#pragma unroll
    for (int j = 0; j < DOUT; ++j) wR[j] = W_root[lane * DOUT + j];
#pragma unroll
    for (int j = 0; j < DOUT; ++j) bj[j] = bias_v[j];

    for (int node = wid; node < N_NODES; node += nwaves) {
        int c = cnt[node];
        int bl = bucket[(size_t)node * CAP + lane];
        float xv = in[(size_t)node * D + lane];
        float agg = gather_mean(in, lane, c, bl);

        float p[DOUT];
#pragma unroll
        for (int j = 0; j < DOUT; ++j) p[j] = agg * wO[j] + xv * wR[j];
        // reduce each p[j] across the 64 lanes (result uniform in-wave)
#pragma unroll
        for (int j = 0; j < DOUT; ++j) {
            float v = p[j];
            v += __shfl_xor(v, 32);
            v += __shfl_xor(v, 16);
            v += __shfl_xor(v, 8);
            v += __shfl_xor(v, 4);
            v += __shfl_xor(v, 2);
            v += __shfl_xor(v, 1);
            p[j] = v + bj[j];
        }
        // in-register log_softmax over the 10 logits
        float m = p[0];
#pragma unroll
        for (int j = 1; j < DOUT; ++j) m = fmaxf(m, p[j]);
        float s = 0.f;
#pragma unroll
        for (int j = 0; j < DOUT; ++j) s += expf(p[j] - m);
        float mls = m + logf(s);
        // lane j < 10 writes logits[j] - (m + log s); static-index select cascade
        float v = p[0];
#pragma unroll
        for (int j = 1; j < DOUT; ++j) v = (lane == j) ? p[j] : v;
        if (lane < DOUT) out[(size_t)node * DOUT + lane] = v - mls;
    }
}

extern "C" void kernel_launch(void* const* d_in, const int* in_sizes, int n_in,
                              void* d_out, int out_size, void* d_ws, size_t ws_size,
                              hipStream_t stream) {
    const float* x       = (const float*)d_in[0];
    const int*   ei      = (const int*)d_in[1];
    const int*   src     = ei;            // edge_index[0]
    const int*   dst     = ei + N_EDGES;  // edge_index[1]
    const float* W_out0  = (const float*)d_in[2];
    const float* b0      = (const float*)d_in[3];
    const float* W_root0 = (const float*)d_in[4];
    const float* W_out1  = (const float*)d_in[5];
    const float* b1      = (const float*)d_in[6];
    const float* W_root1 = (const float*)d_in[7];
    const float* W_out2  = (const float*)d_in[8];
    const float* b2      = (const float*)d_in[9];
    const float* W_root2 = (const float*)d_in[10];
    float* outp = (float*)d_out;

    // workspace: h0[N*64] f32 | h1[N*64] f32 | cnt[N] i32 | bucket[N*64] i32
    float* h0     = (float*)d_ws;
    float* h1     = h0 + (size_t)N_NODES * D;
    int*   cnt    = (int*)(h1 + (size_t)N_NODES * D);
    int*   bucket = cnt + N_NODES;

    hipMemsetAsync(cnt, 0, N_NODES * sizeof(int), stream);
    fill_kernel<<<(N_EDGES + 255) / 256, 256, 0, stream>>>(src, dst, cnt, bucket);

    // hidden: ~200 VGPR -> 2 blocks/CU -> 512 resident blocks
    const int blocks64 = 512;
    layer64_kernel<<<blocks64, 256, 0, stream>>>(x,  h0, cnt, bucket, W_out0, b0, W_root0);
    layer64_kernel<<<blocks64, 256, 0, stream>>>(h0, h1, cnt, bucket, W_out1, b1, W_root1);
    // output layer: low VGPR -> 8 blocks/CU -> 2048 resident blocks
    layer_out_kernel<<<2048, 256, 0, stream>>>(h1, outp, cnt, bucket, W_out2, b2, W_root2);
}

// Round 4
// 448.296 us; speedup vs baseline: 2.1931x; 1.3118x over previous
//
#include <hip/hip_runtime.h>
#include <hip/hip_bf16.h>
#include <math.h>

#define N_NODES 100000
#define N_EDGES 1600000
#define D 64
#define DOUT 10
#define CAP 64
#define APAD 136   // LDS row stride in bf16 elems: 272B, 16B-aligned, 2-way banks only

typedef __attribute__((ext_vector_type(8))) short short8;
typedef __attribute__((ext_vector_type(4))) float f32x4;

__device__ __forceinline__ unsigned short f2bf(float f) {
    __hip_bfloat16 h = __float2bfloat16(f);
    return __builtin_bit_cast(unsigned short, h);
}
__device__ __forceinline__ float bf2f(unsigned short u) {
    __hip_bfloat16 h = __builtin_bit_cast(__hip_bfloat16, u);
    return __bfloat162float(h);
}

// ---------------- bucket build: one int atomic per edge ----------------
__global__ void fill_kernel(const int* __restrict__ src, const int* __restrict__ dst,
                            int* __restrict__ cnt, int* __restrict__ bucket) {
    int e = blockIdx.x * blockDim.x + threadIdx.x;
    if (e >= N_EDGES) return;
    int d = dst[e];
    int p = atomicAdd(&cnt[d], 1);
    if (p < CAP) bucket[d * CAP + p] = src[e];
}

// ---------------- x (f32) -> xb (bf16), 4 elems/thread ----------------
__global__ void cvt_kernel(const float* __restrict__ x, unsigned short* __restrict__ xb) {
    int i = blockIdx.x * blockDim.x + threadIdx.x;
    if (i * 4 >= N_NODES * D) return;
    float4 v = *(const float4*)&x[i * 4];
    ushort4 o;
    o.x = f2bf(v.x); o.y = f2bf(v.y); o.z = f2bf(v.z); o.w = f2bf(v.w);
    *(ushort4*)&xb[i * 4] = o;
}

// --------- pre-transpose weights to Wt[col j][k] bf16 (k<64: W_out, k>=64: W_root) ---------
__global__ void prep_w_kernel(const float* __restrict__ W_out0, const float* __restrict__ W_root0,
                              const float* __restrict__ W_out1, const float* __restrict__ W_root1,
                              const float* __restrict__ W_out2, const float* __restrict__ W_root2,
                              unsigned short* __restrict__ Wt0, unsigned short* __restrict__ Wt1,
                              unsigned short* __restrict__ Wt2) {
    int idx = blockIdx.x * blockDim.x + threadIdx.x;
    if (idx < 8192) {
        int j = idx >> 7, k = idx & 127;
        float v = k < 64 ? W_out0[k * D + j] : W_root0[(k - 64) * D + j];
        Wt0[idx] = f2bf(v);
    } else if (idx < 16384) {
        int t = idx - 8192;
        int j = t >> 7, k = t & 127;
        float v = k < 64 ? W_out1[k * D + j] : W_root1[(k - 64) * D + j];
        Wt1[t] = f2bf(v);
    } else if (idx < 16384 + 2048) {
        int t = idx - 16384;
        int j = t >> 7, k = t & 127;
        float v = 0.f;
        if (j < DOUT) v = k < 64 ? W_out2[k * DOUT + j] : W_root2[(k - 64) * DOUT + j];
        Wt2[t] = f2bf(v);
    }
}

// gather + mean for one node; lane = feature. 8 independent chains in flight.
__device__ __forceinline__ float gather_mean_bf(const unsigned short* __restrict__ in,
                                                int lane, int c, int bl) {
    int cc = c < CAP ? c : CAP;
    float a0 = 0.f, a1 = 0.f, a2 = 0.f, a3 = 0.f,
          a4 = 0.f, a5 = 0.f, a6 = 0.f, a7 = 0.f;
    int k = 0;
    for (; k + 8 <= cc; k += 8) {
        int s0 = __builtin_amdgcn_readlane(bl, k);
        int s1 = __builtin_amdgcn_readlane(bl, k + 1);
        int s2 = __builtin_amdgcn_readlane(bl, k + 2);
        int s3 = __builtin_amdgcn_readlane(bl, k + 3);
        int s4 = __builtin_amdgcn_readlane(bl, k + 4);
        int s5 = __builtin_amdgcn_readlane(bl, k + 5);
        int s6 = __builtin_amdgcn_readlane(bl, k + 6);
        int s7 = __builtin_amdgcn_readlane(bl, k + 7);
        a0 += bf2f(in[(size_t)s0 * D + lane]);
        a1 += bf2f(in[(size_t)s1 * D + lane]);
        a2 += bf2f(in[(size_t)s2 * D + lane]);
        a3 += bf2f(in[(size_t)s3 * D + lane]);
        a4 += bf2f(in[(size_t)s4 * D + lane]);
        a5 += bf2f(in[(size_t)s5 * D + lane]);
        a6 += bf2f(in[(size_t)s6 * D + lane]);
        a7 += bf2f(in[(size_t)s7 * D + lane]);
    }
    for (; k < cc; ++k) {
        int s = __builtin_amdgcn_readlane(bl, k);
        a0 += bf2f(in[(size_t)s * D + lane]);
    }
    float agg = ((a0 + a1) + (a2 + a3)) + ((a4 + a5) + (a6 + a7));
    return agg / (float)(c > 0 ? c : 1);
}

// ---------------- hidden layer: 64-node tile; gather -> LDS A[64][128] -> MFMA ----------------
// A = [agg | x] bf16; C = A @ Wcat (K=128) via mfma_f32_16x16x32_bf16; ReLU; bf16 out.
__global__ __launch_bounds__(256) void layer_mfma_kernel(
    const unsigned short* __restrict__ in, unsigned short* __restrict__ out,
    const int* __restrict__ cnt, const int* __restrict__ bucket,
    const unsigned short* __restrict__ Wt_g, const float* __restrict__ bias_v) {
    __shared__ __align__(16) unsigned short A[64 * APAD];
    __shared__ __align__(16) unsigned short Wt[64 * APAD];
    int tid = threadIdx.x;
    for (int idx = tid; idx < 64 * 128; idx += 256) {
        int j = idx >> 7, k = idx & 127;
        Wt[j * APAD + k] = Wt_g[idx];   // global coalesced, LDS contiguous
    }
    int lane = tid & 63;
    int w = tid >> 6;
    int base = blockIdx.x * 64;

    // gather phase: wave w fills A rows w*16 .. w*16+15
    for (int i = 0; i < 16; ++i) {
        int nl = w * 16 + i;
        int node = base + nl;
        float agg = 0.f, xv = 0.f;
        if (node < N_NODES) {
            int c = cnt[node];
            int bl = bucket[(size_t)node * CAP + lane];   // one coalesced 256B read
            xv = bf2f(in[(size_t)node * D + lane]);
            agg = gather_mean_bf(in, lane, c, bl);
        }
        A[nl * APAD + lane] = f2bf(agg);
        A[nl * APAD + 64 + lane] = f2bf(xv);
    }
    __syncthreads();

    // MFMA phase: wave w computes rows w*16..+15 x all 64 cols, K=128
    int r16 = lane & 15, g4 = lane >> 4;
    f32x4 acc[4] = {{0.f,0.f,0.f,0.f},{0.f,0.f,0.f,0.f},{0.f,0.f,0.f,0.f},{0.f,0.f,0.f,0.f}};
    int arow = w * 16 + r16;
#pragma unroll
    for (int ks = 0; ks < 4; ++ks) {
        int koff = ks * 32 + g4 * 8;
        short8 a = *(const short8*)&A[arow * APAD + koff];
#pragma unroll
        for (int n = 0; n < 4; ++n) {
            short8 b = *(const short8*)&Wt[(n * 16 + r16) * APAD + koff];
            acc[n] = __builtin_amdgcn_mfma_f32_16x16x32_bf16(a, b, acc[n], 0, 0, 0);
        }
    }
#pragma unroll
    for (int n = 0; n < 4; ++n) {
        int col = n * 16 + r16;
        float bias = bias_v[col];
#pragma unroll
        for (int r = 0; r < 4; ++r) {
            int node = base + w * 16 + g4 * 4 + r;
            if (node < N_NODES) {
                float v = fmaxf(acc[n][r] + bias, 0.f);
                out[(size_t)node * D + col] = f2bf(v);
            }
        }
    }
}

// ---------------- output layer: same tile; N=16 (10 real cols); fused log_softmax ----------------
__global__ __launch_bounds__(256) void layer_out_mfma_kernel(
    const unsigned short* __restrict__ in, float* __restrict__ out,
    const int* __restrict__ cnt, const int* __restrict__ bucket,
    const unsigned short* __restrict__ Wt_g, const float* __restrict__ bias_v) {
    __shared__ __align__(16) unsigned short A[64 * APAD];
    __shared__ __align__(16) unsigned short Wt[16 * APAD];
    int tid = threadIdx.x;
    for (int idx = tid; idx < 16 * 128; idx += 256) {
        int j = idx >> 7, k = idx & 127;
        Wt[j * APAD + k] = Wt_g[idx];
    }
    int lane = tid & 63;
    int w = tid >> 6;
    int base = blockIdx.x * 64;

    for (int i = 0; i < 16; ++i) {
        int nl = w * 16 + i;
        int node = base + nl;
        float agg = 0.f, xv = 0.f;
        if (node < N_NODES) {
            int c = cnt[node];
            int bl = bucket[(size_t)node * CAP + lane];
            xv = bf2f(in[(size_t)node * D + lane]);
            agg = gather_mean_bf(in, lane, c, bl);
        }
        A[nl * APAD + lane] = f2bf(agg);
        A[nl * APAD + 64 + lane] = f2bf(xv);
    }
    __syncthreads();

    int r16 = lane & 15, g4 = lane >> 4;
    f32x4 acc = {0.f, 0.f, 0.f, 0.f};
    int arow = w * 16 + r16;
#pragma unroll
    for (int ks = 0; ks < 4; ++ks) {
        int koff = ks * 32 + g4 * 8;
        short8 a = *(const short8*)&A[arow * APAD + koff];
        short8 b = *(const short8*)&Wt[r16 * APAD + koff];
        acc = __builtin_amdgcn_mfma_f32_16x16x32_bf16(a, b, acc, 0, 0, 0);
    }
    float bias = r16 < DOUT ? bias_v[r16] : -1e30f;   // pad cols -> exp()=0
#pragma unroll
    for (int r = 0; r < 4; ++r) {
        float v = acc[r] + bias;
        float m = v;
        m = fmaxf(m, __shfl_xor(m, 1, 16));
        m = fmaxf(m, __shfl_xor(m, 2, 16));
        m = fmaxf(m, __shfl_xor(m, 4, 16));
        m = fmaxf(m, __shfl_xor(m, 8, 16));
        float e = expf(v - m);
        float s = e;
        s += __shfl_xor(s, 1, 16);
        s += __shfl_xor(s, 2, 16);
        s += __shfl_xor(s, 4, 16);
        s += __shfl_xor(s, 8, 16);
        int node = base + w * 16 + g4 * 4 + r;
        if (node < N_NODES && r16 < DOUT)
            out[(size_t)node * DOUT + r16] = v - m - logf(s);
    }
}

extern "C" void kernel_launch(void* const* d_in, const int* in_sizes, int n_in,
                              void* d_out, int out_size, void* d_ws, size_t ws_size,
                              hipStream_t stream) {
    const float* x       = (const float*)d_in[0];
    const int*   ei      = (const int*)d_in[1];
    const int*   src     = ei;            // edge_index[0]
    const int*   dst     = ei + N_EDGES;  // edge_index[1]
    const float* W_out0  = (const float*)d_in[2];
    const float* b0      = (const float*)d_in[3];
    const float* W_root0 = (const float*)d_in[4];
    const float* W_out1  = (const float*)d_in[5];
    const float* b1      = (const float*)d_in[6];
    const float* W_root1 = (const float*)d_in[7];
    const float* W_out2  = (const float*)d_in[8];
    const float* b2      = (const float*)d_in[9];
    const float* W_root2 = (const float*)d_in[10];
    float* outp = (float*)d_out;

    // ws: xb | h0 | h1 (bf16, N*64 each) | Wt0 | Wt1 (64*128 bf16) | Wt2 (16*128 bf16)
    //     | cnt (N i32) | bucket (N*64 i32)   -- total ~64.4 MB
    unsigned short* xb  = (unsigned short*)d_ws;
    unsigned short* h0  = xb + (size_t)N_NODES * D;
    unsigned short* h1  = h0 + (size_t)N_NODES * D;
    unsigned short* Wt0 = h1 + (size_t)N_NODES * D;
    unsigned short* Wt1 = Wt0 + 64 * 128;
    unsigned short* Wt2 = Wt1 + 64 * 128;
    int* cnt    = (int*)(Wt2 + 16 * 128);
    int* bucket = cnt + N_NODES;

    hipMemsetAsync(cnt, 0, N_NODES * sizeof(int), stream);
    fill_kernel<<<(N_EDGES + 255) / 256, 256, 0, stream>>>(src, dst, cnt, bucket);
    cvt_kernel<<<(N_NODES * D / 4 + 255) / 256, 256, 0, stream>>>(x, xb);
    prep_w_kernel<<<(16384 + 2048 + 255) / 256, 256, 0, stream>>>(
        W_out0, W_root0, W_out1, W_root1, W_out2, W_root2, Wt0, Wt1, Wt2);

    const int tiles = (N_NODES + 63) / 64;  // 1563
    layer_mfma_kernel<<<tiles, 256, 0, stream>>>(xb, h0, cnt, bucket, Wt0, b0);
    layer_mfma_kernel<<<tiles, 256, 0, stream>>>(h0, h1, cnt, bucket, Wt1, b1);
    layer_out_mfma_kernel<<<tiles, 256, 0, stream>>>(h1, outp, cnt, bucket, Wt2, b2);
}